// Round 1
// baseline (1457.515 us; speedup 1.0000x reference)
//
#include <hip/hip_runtime.h>
#include <math.h>

#define HID 128
#define DEPTH 4

// ---------------------------------------------------------------- node embed
__global__ void k_node_embed(const float* __restrict__ x, const float* __restrict__ nw,
                             const float* __restrict__ nb, float* __restrict__ h, int N) {
    int idx = blockIdx.x * blockDim.x + threadIdx.x;
    if (idx >= N * HID) return;
    int n = idx >> 7, c = idx & 127;
    float acc = nb[c];
#pragma unroll
    for (int d = 0; d < 4; ++d) acc += x[n * 4 + d] * nw[d * HID + c];
    h[idx] = acc;
}

// ---------------------------------------------------------------- CSR build
__global__ void k_hist(const int* __restrict__ dst, int* __restrict__ deg, int E) {
    int e = blockIdx.x * 256 + threadIdx.x;
    if (e < E) atomicAdd(&deg[dst[e]], 1);
}

__global__ void k_scan(const int* __restrict__ deg, int* __restrict__ offs,
                       int* __restrict__ cursor, int N) {
    __shared__ int sh[256];
    int running = 0;
    for (int base = 0; base < N; base += 256) {
        int i = base + (int)threadIdx.x;
        int v = (i < N) ? deg[i] : 0;
        sh[threadIdx.x] = v;
        __syncthreads();
        for (int off = 1; off < 256; off <<= 1) {
            int add = (threadIdx.x >= (unsigned)off) ? sh[threadIdx.x - off] : 0;
            __syncthreads();
            sh[threadIdx.x] += add;
            __syncthreads();
        }
        int incl = sh[threadIdx.x];
        if (i < N) { int ex = running + incl - v; offs[i] = ex; cursor[i] = ex; }
        int tot = sh[255];
        __syncthreads();
        running += tot;
    }
    if (threadIdx.x == 0) offs[N] = running;
}

__global__ void k_scatter(const int* __restrict__ dst, int* cursor,
                          int* __restrict__ eord, int E) {
    int e = blockIdx.x * 256 + threadIdx.x;
    if (e < E) { int p = atomicAdd(&cursor[dst[e]], 1); eord[p] = e; }
}

__global__ void k_boffs(const int* __restrict__ batch, int* __restrict__ boffs, int N) {
    __shared__ int bc[64];
    if (threadIdx.x < 64) bc[threadIdx.x] = 0;
    __syncthreads();
    for (int n = threadIdx.x; n < N; n += blockDim.x) atomicAdd(&bc[batch[n]], 1);
    __syncthreads();
    if (threadIdx.x == 0) {
        int run = 0;
        for (int b = 0; b < 64; ++b) { boffs[b] = run; run += bc[b]; }
        boffs[64] = run;
    }
}

// ---------------------------------------------------------------- per-node linear (A1,A2,a1,a2)
__global__ void k_node_lin(const float* __restrict__ h, const float* __restrict__ linw,
                           const float* __restrict__ linb, const float* __restrict__ attw,
                           const float* __restrict__ attb,
                           float* __restrict__ A1, float* __restrict__ A2,
                           float* __restrict__ a1, float* __restrict__ a2, int N) {
    __shared__ float hsh[8][HID];
    __shared__ float red[256];
    int nb = blockIdx.x * 8;
    int tid = threadIdx.x;
    for (int i = tid; i < 8 * HID; i += 256) {
        int n = i >> 7, c = i & 127;
        int gn = nb + n;
        hsh[n][c] = (gn < N) ? h[gn * HID + c] : 0.f;
    }
    __syncthreads();
    int c = tid & 127, r = tid >> 7;
    const float* Wd = linw;
    const float* Ws = linw + 128 * HID;
    float acc1[4], acc2[4];
#pragma unroll
    for (int j = 0; j < 4; ++j) { acc1[j] = 0.f; acc2[j] = 0.f; }
#pragma unroll 4
    for (int k = 0; k < HID; ++k) {
        float wd = Wd[k * HID + c];
        float ws = Ws[k * HID + c];
#pragma unroll
        for (int j = 0; j < 4; ++j) {
            float hv = hsh[r * 4 + j][k];
            acc1[j] += hv * wd;
            acc2[j] += hv * ws;
        }
    }
#pragma unroll
    for (int j = 0; j < 4; ++j) {
        int gn = nb + r * 4 + j;
        if (gn < N) {
            A1[gn * HID + c] = acc1[j] + linb[c];
            A2[gn * HID + c] = acc2[j];
        }
    }
    // attention dots: r==0 threads -> dst part, r==1 threads -> src part
    float aw = (r == 0) ? attw[c] : attw[128 + c];
    for (int n = 0; n < 8; ++n) {
        red[tid] = hsh[n][c] * aw;
        __syncthreads();
        for (int off = 64; off > 0; off >>= 1) {
            if (c < off) red[r * 128 + c] += red[r * 128 + c + off];
            __syncthreads();
        }
        if (c == 0) {
            int gn = nb + n;
            if (gn < N) {
                if (r == 0) a1[gn] = red[0] + attb[0];
                else        a2[gn] = red[128];
            }
        }
        __syncthreads();
    }
}

// ---------------------------------------------------------------- Fourier-Kolmogorov GEMM
// C[32 nodes x 128 cols] per block; A = sin(2pi f h)+cos(2pi f h) built on the fly.
#define FK_TN 32
__global__ __launch_bounds__(256) void k_fk(const float* __restrict__ h,
                                            const float* __restrict__ fkw,
                                            const float* __restrict__ fkb,
                                            float* __restrict__ hfk, int N) {
    __shared__ float hsh[FK_TN][HID + 1];
    __shared__ float ash[32][FK_TN];
    int nb = blockIdx.x * FK_TN;
    int tid = threadIdx.x;
    for (int i = tid; i < FK_TN * HID; i += 256) {
        int nn = i >> 7, cc = i & 127;
        int gn = nb + nn;
        hsh[nn][cc] = (gn < N) ? h[gn * HID + cc] : 0.f;
    }
    int cg = tid & 31, ng = tid >> 5;
    int c0 = cg * 4, n0 = ng * 4;
    float acc[4][4];
#pragma unroll
    for (int j = 0; j < 4; ++j)
#pragma unroll
        for (int q = 0; q < 4; ++q) acc[j][q] = 0.f;

    for (int kc = 0; kc < 1024; kc += 32) {
        __syncthreads();
        // stage trig chunk: 32 k x 32 nodes
        for (int i = tid; i < 32 * FK_TN; i += 256) {
            int kk = i >> 5, nn = i & 31;
            int ki = kc + kk;
            int fr = ki >> 7, ii = ki & 127;
            float hv = hsh[nn][ii];
            float fk = 6.2831855f * (float)(fr + 1);
            float ang = fk * hv;
            float sv, cv;
            __sincosf(ang, &sv, &cv);
            ash[kk][nn] = sv + cv;
        }
        __syncthreads();
#pragma unroll 8
        for (int kk = 0; kk < 32; ++kk) {
            const float4 w = *(const float4*)&fkw[(kc + kk) * HID + c0];
            const float4 a = *(const float4*)&ash[kk][n0];
            acc[0][0] += a.x * w.x; acc[0][1] += a.x * w.y; acc[0][2] += a.x * w.z; acc[0][3] += a.x * w.w;
            acc[1][0] += a.y * w.x; acc[1][1] += a.y * w.y; acc[1][2] += a.y * w.z; acc[1][3] += a.y * w.w;
            acc[2][0] += a.z * w.x; acc[2][1] += a.z * w.y; acc[2][2] += a.z * w.z; acc[2][3] += a.z * w.w;
            acc[3][0] += a.w * w.x; acc[3][1] += a.w * w.y; acc[3][2] += a.w * w.z; acc[3][3] += a.w * w.w;
        }
    }
    float4 bv = *(const float4*)&fkb[c0];
#pragma unroll
    for (int j = 0; j < 4; ++j) {
        int gn = nb + n0 + j;
        if (gn < N) {
            float4 o;
            o.x = acc[j][0] + bv.x; o.y = acc[j][1] + bv.y;
            o.z = acc[j][2] + bv.z; o.w = acc[j][3] + bv.w;
            *(float4*)&hfk[gn * HID + c0] = o;
        }
    }
}

// ---------------------------------------------------------------- edge conv (CSR, no atomics)
__global__ void k_edge(const float* __restrict__ A1, const float* __restrict__ A2,
                       const float* __restrict__ a1, const float* __restrict__ a2,
                       const int* __restrict__ src, const float* __restrict__ ea,
                       const int* __restrict__ offs, const int* __restrict__ eord,
                       const float* __restrict__ linw3, const float* __restrict__ attw3,
                       float* __restrict__ hconv, int N) {
    __shared__ float w3[3 * HID];
    __shared__ float aw3[3];
    int n = blockIdx.x;
    int tid = threadIdx.x;  // 128 threads
    for (int i = tid; i < 3 * HID; i += 128) w3[i] = linw3[i];
    if (tid < 3) aw3[tid] = attw3[tid];
    __syncthreads();
    int c = tid;
    float A1c = A1[n * HID + c];
    float a1n = a1[n];
    float accum = 0.f;
    int s0 = offs[n], s1 = offs[n + 1];
    for (int idx = s0; idx < s1; ++idx) {
        int e = eord[idx];
        int s = src[e];
        float e0 = ea[e * 3 + 0], e1 = ea[e * 3 + 1], e2 = ea[e * 3 + 2];
        float logit = a1n + a2[s] + e0 * aw3[0] + e1 * aw3[1] + e2 * aw3[2];
        float alpha = 1.f / (1.f + __expf(-logit));
        float pre = A1c + A2[s * HID + c] + e0 * w3[0 * HID + c] + e1 * w3[1 * HID + c] + e2 * w3[2 * HID + c];
        accum += alpha * pre;
    }
    hconv[n * HID + c] = accum;
}

// ---------------------------------------------------------------- batchnorm
__global__ void k_bn_stats(const float* __restrict__ hconv, const float* __restrict__ hfk,
                           double* __restrict__ stats, int N) {
    int c = threadIdx.x & 127, half = threadIdx.x >> 7;
    float s = 0.f, s2 = 0.f;
    for (int n = blockIdx.x * 2 + half; n < N; n += gridDim.x * 2) {
        float v = hconv[n * HID + c] + hfk[n * HID + c];
        s += v; s2 += v * v;
    }
    __shared__ float sh[256], sh2[256];
    sh[threadIdx.x] = s; sh2[threadIdx.x] = s2;
    __syncthreads();
    if (half == 0) {
        s = sh[c] + sh[128 + c];
        s2 = sh2[c] + sh2[128 + c];
        atomicAdd(&stats[c], (double)s);
        atomicAdd(&stats[128 + c], (double)s2);
    }
}

__global__ void k_bn_final(const double* __restrict__ stats, const float* __restrict__ g,
                           const float* __restrict__ b, float* __restrict__ ss, int N) {
    int c = threadIdx.x;
    double mu = stats[c] / (double)N;
    double var = stats[128 + c] / (double)N - mu * mu;
    double inv = 1.0 / sqrt(var + 1e-5);
    float sc = (float)((double)g[c] * inv);
    ss[c] = sc;
    ss[128 + c] = b[c] - (float)(mu * (double)g[c] * inv);
}

__global__ void k_bn_apply(const float* __restrict__ hconv, const float* __restrict__ hfk,
                           const float* __restrict__ ss, float* __restrict__ h, int N) {
    int idx = blockIdx.x * blockDim.x + threadIdx.x;
    if (idx >= N * HID) return;
    int c = idx & 127;
    float v = hconv[idx] + hfk[idx];
    float o = v * ss[c] + ss[128 + c];
    h[idx] = fmaxf(o, 0.f);
}

// ---------------------------------------------------------------- attention pool
__global__ void k_score(const float* __restrict__ h, const float* __restrict__ pw,
                        const float* __restrict__ pb, float* __restrict__ s, int N) {
    __shared__ float red[256];
    int c = threadIdx.x & 127, r = threadIdx.x >> 7;
    int n = blockIdx.x * 2 + r;
    float p = (n < N) ? h[n * HID + c] * pw[c] : 0.f;
    red[threadIdx.x] = p;
    __syncthreads();
    for (int off = 64; off > 0; off >>= 1) {
        if (c < off) red[r * 128 + c] += red[r * 128 + c + off];
        __syncthreads();
    }
    if (c == 0 && n < N) s[n] = red[r * 128] + pb[0];
}

__global__ void k_softmax_reduce(const float* __restrict__ s, float* __restrict__ mz, int N) {
    __shared__ float red[256];
    float m = -INFINITY;
    for (int n = threadIdx.x; n < N; n += 256) m = fmaxf(m, s[n]);
    red[threadIdx.x] = m;
    __syncthreads();
    for (int off = 128; off > 0; off >>= 1) {
        if (threadIdx.x < (unsigned)off) red[threadIdx.x] = fmaxf(red[threadIdx.x], red[threadIdx.x + off]);
        __syncthreads();
    }
    m = red[0];
    __syncthreads();
    float z = 0.f;
    for (int n = threadIdx.x; n < N; n += 256) z += __expf(s[n] - m);
    red[threadIdx.x] = z;
    __syncthreads();
    for (int off = 128; off > 0; off >>= 1) {
        if (threadIdx.x < (unsigned)off) red[threadIdx.x] += red[threadIdx.x + off];
        __syncthreads();
    }
    if (threadIdx.x == 0) { mz[0] = m; mz[1] = red[0]; }
}

__global__ void k_pool(const float* __restrict__ h, const float* __restrict__ s,
                       const float* __restrict__ mz, const int* __restrict__ boffs,
                       float* __restrict__ pooled) {
    int b = blockIdx.x, c = threadIdx.x;
    float m = mz[0], Z = mz[1];
    float acc = 0.f;
    int n0 = boffs[b], n1 = boffs[b + 1];
    for (int n = n0; n < n1; ++n) acc += __expf(s[n] - m) * h[n * HID + c];
    pooled[b * HID + c] = acc / Z;
}

// ---------------------------------------------------------------- heads
__global__ void k_head(const float* __restrict__ pooled, const float* __restrict__ sg_table,
                       const int* __restrict__ space_group,
                       const float* __restrict__ hw1, const float* __restrict__ hb1,
                       const float* __restrict__ ew2, const float* __restrict__ eb2,
                       const float* __restrict__ sw2, const float* __restrict__ sb2,
                       const float* __restrict__ cw2, const float* __restrict__ cb2,
                       const float* __restrict__ mw2, const float* __restrict__ mb2,
                       float* __restrict__ out, int B) {
    __shared__ float comb[256];
    __shared__ float zsh[128];
    int b = blockIdx.x, t = threadIdx.x;
    comb[t] = pooled[b * HID + t];
    comb[128 + t] = sg_table[space_group[b] * HID + t];
    __syncthreads();
    const int od[4] = {1, 3, 7, 3};
    const int base[4] = {0, 64, 256, 704};
    for (int i = 0; i < 4; ++i) {
        float z = hb1[i * HID + t];
#pragma unroll 8
        for (int k = 0; k < 256; ++k) z += comb[k] * hw1[(i * 256 + k) * HID + t];
        z = fmaxf(z, 0.f);
        zsh[t] = z;
        __syncthreads();
        const float* w2 = (i == 0) ? ew2 : (i == 1) ? sw2 : (i == 2) ? cw2 : mw2;
        const float* b2 = (i == 0) ? eb2 : (i == 1) ? sb2 : (i == 2) ? cb2 : mb2;
        if (t < od[i]) {
            float o = b2[t];
            for (int c = 0; c < HID; ++c) o += zsh[c] * w2[c * od[i] + t];
            out[base[i] + b * od[i] + t] = o;
        }
        __syncthreads();
    }
}

// ---------------------------------------------------------------- launch
extern "C" void kernel_launch(void* const* d_in, const int* in_sizes, int n_in,
                              void* d_out, int out_size, void* d_ws, size_t ws_size,
                              hipStream_t stream) {
    const float* x          = (const float*)d_in[0];
    const int*   edge_index = (const int*)d_in[1];
    const float* edge_attr  = (const float*)d_in[2];
    const int*   batch      = (const int*)d_in[3];
    const int*   space_group= (const int*)d_in[4];
    const float* node_w     = (const float*)d_in[5];
    const float* node_b     = (const float*)d_in[6];
    const float* sg_table   = (const float*)d_in[7];
    const float* lin_w      = (const float*)d_in[8];
    const float* lin_b      = (const float*)d_in[9];
    const float* att_w      = (const float*)d_in[10];
    const float* att_b      = (const float*)d_in[11];
    const float* fk_w       = (const float*)d_in[12];
    const float* fk_b       = (const float*)d_in[13];
    const float* bn_g       = (const float*)d_in[14];
    const float* bn_b       = (const float*)d_in[15];
    const float* pool_w     = (const float*)d_in[16];
    const float* pool_b     = (const float*)d_in[17];
    const float* head_w1    = (const float*)d_in[18];
    const float* head_b1    = (const float*)d_in[19];
    const float* ew2 = (const float*)d_in[20]; const float* eb2 = (const float*)d_in[21];
    const float* sw2 = (const float*)d_in[22]; const float* sb2 = (const float*)d_in[23];
    const float* cw2 = (const float*)d_in[24]; const float* cb2 = (const float*)d_in[25];
    const float* mw2 = (const float*)d_in[26]; const float* mb2 = (const float*)d_in[27];
    float* out = (float*)d_out;

    const int N = in_sizes[3];
    const int E = in_sizes[1] / 2;
    const int B = in_sizes[4];
    const int* src = edge_index;
    const int* dst = edge_index + E;

    // workspace carve-up (256B aligned)
    char* w = (char*)d_ws;
    auto alloc = [&](size_t bytes) { char* p = w; w += (bytes + 255) & ~(size_t)255; return p; };
    float*  h      = (float*)alloc((size_t)N * HID * 4);
    float*  A1     = (float*)alloc((size_t)N * HID * 4);
    float*  A2     = (float*)alloc((size_t)N * HID * 4);
    float*  hfk    = (float*)alloc((size_t)N * HID * 4);
    float*  hconv  = (float*)alloc((size_t)N * HID * 4);
    float*  a1     = (float*)alloc((size_t)N * 4);
    float*  a2     = (float*)alloc((size_t)N * 4);
    float*  sbuf   = (float*)alloc((size_t)N * 4);
    int*    deg    = (int*)alloc((size_t)N * 4);
    int*    cursor = (int*)alloc((size_t)N * 4);
    int*    offs   = (int*)alloc((size_t)(N + 1) * 4);
    int*    eord   = (int*)alloc((size_t)E * 4);
    int*    boffs  = (int*)alloc((size_t)(B + 1) * 4);
    double* stats  = (double*)alloc(256 * 8);
    float*  ss     = (float*)alloc(256 * 4);
    float*  mz     = (float*)alloc(2 * 4);
    float*  pooled = (float*)alloc((size_t)B * HID * 4);

    // CSR build (per call; same work every call)
    hipMemsetAsync(deg, 0, (size_t)N * 4, stream);
    k_hist<<<(E + 255) / 256, 256, 0, stream>>>(dst, deg, E);
    k_scan<<<1, 256, 0, stream>>>(deg, offs, cursor, N);
    k_scatter<<<(E + 255) / 256, 256, 0, stream>>>(dst, cursor, eord, E);
    k_boffs<<<1, 256, 0, stream>>>(batch, boffs, N);

    k_node_embed<<<(N * HID + 255) / 256, 256, 0, stream>>>(x, node_w, node_b, h, N);

    for (int l = 0; l < DEPTH; ++l) {
        const float* linw_l = lin_w + (size_t)l * 259 * HID;
        k_node_lin<<<(N + 7) / 8, 256, 0, stream>>>(
            h, linw_l, lin_b + l * HID, att_w + (size_t)l * 259, att_b + l,
            A1, A2, a1, a2, N);
        k_fk<<<(N + FK_TN - 1) / FK_TN, 256, 0, stream>>>(
            h, fk_w + (size_t)l * 1024 * HID, fk_b + l * HID, hfk, N);
        k_edge<<<N, 128, 0, stream>>>(
            A1, A2, a1, a2, src, edge_attr, offs, eord,
            linw_l + 256 * HID, att_w + (size_t)l * 259 + 256, hconv, N);
        hipMemsetAsync(stats, 0, 256 * 8, stream);
        k_bn_stats<<<128, 256, 0, stream>>>(hconv, hfk, stats, N);
        k_bn_final<<<1, 128, 0, stream>>>(stats, bn_g + l * HID, bn_b + l * HID, ss, N);
        k_bn_apply<<<(N * HID + 255) / 256, 256, 0, stream>>>(hconv, hfk, ss, h, N);
    }

    k_score<<<(N + 1) / 2, 256, 0, stream>>>(h, pool_w, pool_b, sbuf, N);
    k_softmax_reduce<<<1, 256, 0, stream>>>(sbuf, mz, N);
    k_pool<<<B, 128, 0, stream>>>(h, sbuf, mz, boffs, pooled);
    k_head<<<B, 128, 0, stream>>>(pooled, sg_table, space_group, head_w1, head_b1,
                                  ew2, eb2, sw2, sb2, cw2, cb2, mw2, mb2, out, B);
}